// Round 1
// baseline (316.979 us; speedup 1.0000x reference)
//
#include <hip/hip_runtime.h>
#include <stdint.h>

#define N_PTS 65536
typedef unsigned long long u64;

// ---------------------------------------------------------------------------
// K1: per-point MLP score (batch 0 only).
//   h1 = relu(W1 x + b1)            6 -> 32
//   v  = relu(W2 h1 + b2)           32 -> 64   (streamed, fused into h3 acc)
//   h3 = relu(Wa v + ba)            64 -> 16
//   u  = relu(Wb h3 + bb)           16 -> 8    (streamed, fused into z acc)
//   z  = Wc u + bc                  8 -> 1
//   score = softplus(z) = max(z,0) + log1p(exp(-|z|))
// ---------------------------------------------------------------------------
__global__ __launch_bounds__(256) void score_kernel(
    const float* __restrict__ src,
    const float* __restrict__ W1, const float* __restrict__ b1,
    const float* __restrict__ W2, const float* __restrict__ b2,
    const float* __restrict__ Wa, const float* __restrict__ ba,
    const float* __restrict__ Wb, const float* __restrict__ bb,
    const float* __restrict__ Wc, const float* __restrict__ bc,
    float* __restrict__ scores)
{
    __shared__ float sW1[192], sb1[32], sW2[2048], sb2[64];
    __shared__ float sWa[1024], sba[16], sWb[128], sbb[8], sWc[8], sbc1[1];
    const int t = threadIdx.x;
    for (int i = t; i < 192;  i += 256) sW1[i] = W1[i];
    for (int i = t; i < 32;   i += 256) sb1[i] = b1[i];
    for (int i = t; i < 2048; i += 256) sW2[i] = W2[i];
    for (int i = t; i < 64;   i += 256) sb2[i] = b2[i];
    for (int i = t; i < 1024; i += 256) sWa[i] = Wa[i];
    for (int i = t; i < 16;   i += 256) sba[i] = ba[i];
    for (int i = t; i < 128;  i += 256) sWb[i] = Wb[i];
    for (int i = t; i < 8;    i += 256) sbb[i] = bb[i];
    for (int i = t; i < 8;    i += 256) sWc[i] = Wc[i];
    if (t == 0) sbc1[0] = bc[0];
    __syncthreads();

    const int n = blockIdx.x * 256 + t;

    float x[6];
    #pragma unroll
    for (int c = 0; c < 6; c++) x[c] = src[c * N_PTS + n];   // batch 0

    float h1[32];
    #pragma unroll
    for (int j = 0; j < 32; j++) {
        float s = sb1[j];
        #pragma unroll
        for (int c = 0; c < 6; c++) s = fmaf(sW1[j * 6 + c], x[c], s);
        h1[j] = fmaxf(s, 0.f);
    }

    // layers 2+3 fused: stream each of the 64 hidden units into 16 accumulators
    float h3[16];
    #pragma unroll
    for (int q = 0; q < 16; q++) h3[q] = sba[q];
    #pragma unroll
    for (int j = 0; j < 64; j++) {
        float s = sb2[j];
        #pragma unroll
        for (int i = 0; i < 32; i++) s = fmaf(sW2[j * 32 + i], h1[i], s);
        s = fmaxf(s, 0.f);
        #pragma unroll
        for (int q = 0; q < 16; q++) h3[q] = fmaf(sWa[q * 64 + j], s, h3[q]);
    }
    #pragma unroll
    for (int q = 0; q < 16; q++) h3[q] = fmaxf(h3[q], 0.f);

    // layers 4+5 fused
    float z = sbc1[0];
    #pragma unroll
    for (int j = 0; j < 8; j++) {
        float s = sbb[j];
        #pragma unroll
        for (int q = 0; q < 16; q++) s = fmaf(sWb[j * 16 + q], h3[q], s);
        s = fmaxf(s, 0.f);
        z = fmaf(sWc[j], s, z);
    }

    const float sp = fmaxf(z, 0.f) + log1pf(expf(-fabsf(z)));
    scores[n] = sp;
}

// ---------------------------------------------------------------------------
// Composite sort key: (float bits of positive score) << 32 | ~index.
// Descending sort => value desc, lower index first on ties (lax.top_k rule).
// softplus > 0 always, so IEEE bits of the score are order-preserving.
// ---------------------------------------------------------------------------

__global__ __launch_bounds__(256) void block_topk_kernel(
    const float* __restrict__ scores, u64* __restrict__ cand)
{
    __shared__ u64 keys[1024];
    const int t = threadIdx.x;
    const int base = blockIdx.x * 1024;
    for (int i = t; i < 1024; i += 256) {
        const int n = base + i;
        const unsigned vb = __float_as_uint(scores[n]);
        keys[i] = ((u64)vb << 32) | (unsigned)(~n);
    }
    __syncthreads();
    // bitonic sort, descending
    for (int k = 2; k <= 1024; k <<= 1) {
        for (int j = k >> 1; j > 0; j >>= 1) {
            for (int i = t; i < 1024; i += 256) {
                const int ixj = i ^ j;
                if (ixj > i) {
                    const u64 a = keys[i], b = keys[ixj];
                    const bool desc = (i & k) == 0;
                    if (desc ? (a < b) : (a > b)) { keys[i] = b; keys[ixj] = a; }
                }
            }
            __syncthreads();
        }
    }
    if (t < 64) cand[blockIdx.x * 64 + t] = keys[t];
}

__global__ __launch_bounds__(256) void final_kernel(
    const u64* __restrict__ cand, const float* __restrict__ src,
    float* __restrict__ out)
{
    __shared__ u64 keys[4096];
    __shared__ int idxs[64];
    const int t = threadIdx.x;
    for (int i = t; i < 4096; i += 256) keys[i] = cand[i];
    __syncthreads();
    for (int k = 2; k <= 4096; k <<= 1) {
        for (int j = k >> 1; j > 0; j >>= 1) {
            for (int i = t; i < 4096; i += 256) {
                const int ixj = i ^ j;
                if (ixj > i) {
                    const u64 a = keys[i], b = keys[ixj];
                    const bool desc = (i & k) == 0;
                    if (desc ? (a < b) : (a > b)) { keys[i] = b; keys[ixj] = a; }
                }
            }
            __syncthreads();
        }
    }
    if (t < 64) idxs[t] = (int)~(unsigned)(keys[t] & 0xFFFFFFFFu);
    __syncthreads();

    // out[b, k, c] = src[b, c, idx[k]]  -> flat e = b*384 + k*6 + c
    for (int e = t; e < 3072; e += 256) {
        const int b  = e / 384;
        const int r  = e % 384;
        const int kk = r / 6;
        const int c  = r % 6;
        out[e] = src[(b * 6 + c) * N_PTS + idxs[kk]];
    }
}

extern "C" void kernel_launch(void* const* d_in, const int* in_sizes, int n_in,
                              void* d_out, int out_size, void* d_ws, size_t ws_size,
                              hipStream_t stream)
{
    const float* src = (const float*)d_in[0];
    // d_in[1] = tgt_pts: unused by the live output
    const float* W1 = (const float*)d_in[2];
    const float* b1 = (const float*)d_in[3];
    const float* W2 = (const float*)d_in[4];
    const float* b2 = (const float*)d_in[5];
    const float* Wa = (const float*)d_in[6];
    const float* ba = (const float*)d_in[7];
    const float* Wb = (const float*)d_in[8];
    const float* bb = (const float*)d_in[9];
    const float* Wc = (const float*)d_in[10];
    const float* bc = (const float*)d_in[11];

    float* scores = (float*)d_ws;                                   // 65536 f32 = 256 KB
    u64*   cand   = (u64*)((char*)d_ws + N_PTS * sizeof(float));    // 4096 u64 = 32 KB
    float* out    = (float*)d_out;                                  // (8,64,6) f32

    score_kernel<<<256, 256, 0, stream>>>(src, W1, b1, W2, b2, Wa, ba,
                                          Wb, bb, Wc, bc, scores);
    block_topk_kernel<<<64, 256, 0, stream>>>(scores, cand);
    final_kernel<<<1, 256, 0, stream>>>(cand, src, out);
}

// Round 2
// 206.826 us; speedup vs baseline: 1.5326x; 1.5326x over previous
//
#include <hip/hip_runtime.h>
#include <stdint.h>

#define N_PTS 65536
#define NBINS 32768      // positive f32 -> bits>>16 in [0, 32768)
#define CAND_CAP 2048
typedef unsigned long long u64;

// ws layout
//   [0      , 256K)  scores  f32[65536]
//   [256K   , 384K)  hist    u32[32768]
//   [384K   , 400K)  cand    u64[2048]
//   [400K   , ... )  meta    i32[4]  {0:cand_count, 1:thresh_bin}

__global__ __launch_bounds__(256) void zero_kernel(unsigned* __restrict__ hist,
                                                   int* __restrict__ meta)
{
    const int i = blockIdx.x * 256 + threadIdx.x;
    if (i < NBINS) hist[i] = 0u;
    if (i < 4) meta[i] = 0;
}

// ---------------------------------------------------------------------------
// K1: per-point MLP score (batch 0 only) + histogram of score high-16 bits.
// ---------------------------------------------------------------------------
__global__ __launch_bounds__(256) void score_kernel(
    const float* __restrict__ src,
    const float* __restrict__ W1, const float* __restrict__ b1,
    const float* __restrict__ W2, const float* __restrict__ b2,
    const float* __restrict__ Wa, const float* __restrict__ ba,
    const float* __restrict__ Wb, const float* __restrict__ bb,
    const float* __restrict__ Wc, const float* __restrict__ bc,
    float* __restrict__ scores, unsigned* __restrict__ hist)
{
    __shared__ float sW1[192], sb1[32], sW2[2048], sb2[64];
    __shared__ float sWa[1024], sba[16], sWb[128], sbb[8], sWc[8], sbc1[1];
    const int t = threadIdx.x;
    for (int i = t; i < 192;  i += 256) sW1[i] = W1[i];
    for (int i = t; i < 32;   i += 256) sb1[i] = b1[i];
    for (int i = t; i < 2048; i += 256) sW2[i] = W2[i];
    for (int i = t; i < 64;   i += 256) sb2[i] = b2[i];
    for (int i = t; i < 1024; i += 256) sWa[i] = Wa[i];
    for (int i = t; i < 16;   i += 256) sba[i] = ba[i];
    for (int i = t; i < 128;  i += 256) sWb[i] = Wb[i];
    for (int i = t; i < 8;    i += 256) sbb[i] = bb[i];
    for (int i = t; i < 8;    i += 256) sWc[i] = Wc[i];
    if (t == 0) sbc1[0] = bc[0];
    __syncthreads();

    const int n = blockIdx.x * 256 + t;

    float x[6];
    #pragma unroll
    for (int c = 0; c < 6; c++) x[c] = src[c * N_PTS + n];   // batch 0

    float h1[32];
    #pragma unroll
    for (int j = 0; j < 32; j++) {
        float s = sb1[j];
        #pragma unroll
        for (int c = 0; c < 6; c++) s = fmaf(sW1[j * 6 + c], x[c], s);
        h1[j] = fmaxf(s, 0.f);
    }

    float h3[16];
    #pragma unroll
    for (int q = 0; q < 16; q++) h3[q] = sba[q];
    #pragma unroll
    for (int j = 0; j < 64; j++) {
        float s = sb2[j];
        #pragma unroll
        for (int i = 0; i < 32; i++) s = fmaf(sW2[j * 32 + i], h1[i], s);
        s = fmaxf(s, 0.f);
        #pragma unroll
        for (int q = 0; q < 16; q++) h3[q] = fmaf(sWa[q * 64 + j], s, h3[q]);
    }
    #pragma unroll
    for (int q = 0; q < 16; q++) h3[q] = fmaxf(h3[q], 0.f);

    float z = sbc1[0];
    #pragma unroll
    for (int j = 0; j < 8; j++) {
        float s = sbb[j];
        #pragma unroll
        for (int q = 0; q < 16; q++) s = fmaf(sWb[j * 16 + q], h3[q], s);
        s = fmaxf(s, 0.f);
        z = fmaf(sWc[j], s, z);
    }

    const float sp = fmaxf(z, 0.f) + log1pf(expf(-fabsf(z)));
    scores[n] = sp;
    atomicAdd(&hist[__float_as_uint(sp) >> 16], 1u);
}

// ---------------------------------------------------------------------------
// K2: find threshold bin T = max bin with suffix-count >= 64.
// One block of 256 threads; 128 bins/thread, chunked suffix-scan.
// ---------------------------------------------------------------------------
__global__ __launch_bounds__(256) void scan_kernel(const unsigned* __restrict__ hist,
                                                   int* __restrict__ meta)
{
    __shared__ unsigned sfx[256];
    __shared__ unsigned binsfx[128];
    __shared__ int c_star;
    const int t = threadIdx.x;

    // per-chunk count: chunk t = bins [t*128, t*128+128)
    unsigned sum = 0;
    const uint4* h4 = (const uint4*)(hist + t * 128);
    #pragma unroll 4
    for (int i = 0; i < 32; i++) {
        uint4 v = h4[i];
        sum += v.x + v.y + v.z + v.w;
    }
    sfx[t] = sum;
    __syncthreads();

    // suffix sum over chunks (Hillis-Steele)
    for (int d = 1; d < 256; d <<= 1) {
        unsigned v = (t + d < 256) ? sfx[t + d] : 0u;
        __syncthreads();
        sfx[t] += v;
        __syncthreads();
    }
    // c* = max chunk with suffix >= 64 (sfx[0] = 65536 so it exists)
    {
        unsigned nxt = (t + 1 < 256) ? sfx[t + 1] : 0u;
        if (sfx[t] >= 64u && nxt < 64u) c_star = t;
    }
    __syncthreads();

    const int base_bin = c_star * 128;
    const unsigned tail = (c_star < 255) ? sfx[c_star + 1] : 0u;  // count of bins >= base+128

    if (t < 128) binsfx[t] = hist[base_bin + t];
    __syncthreads();
    for (int d = 1; d < 128; d <<= 1) {
        unsigned v = 0u;
        if (t < 128 && t + d < 128) v = binsfx[t + d];
        __syncthreads();
        if (t < 128) binsfx[t] += v;
        __syncthreads();
    }
    if (t < 128) {
        const unsigned here = binsfx[t] + tail;
        const unsigned nxt  = (t + 1 < 128) ? binsfx[t + 1] + tail : tail;
        if (here >= 64u && nxt < 64u) meta[1] = base_bin + t;
    }
}

// ---------------------------------------------------------------------------
// K3: compact all points with bin >= T into candidate buffer.
// ---------------------------------------------------------------------------
__global__ __launch_bounds__(256) void compact_kernel(
    const float* __restrict__ scores, int* __restrict__ meta,
    u64* __restrict__ cand)
{
    const int n = blockIdx.x * 256 + threadIdx.x;
    const unsigned vb = __float_as_uint(scores[n]);
    const int T = meta[1];
    if ((int)(vb >> 16) >= T) {
        const int pos = atomicAdd(&meta[0], 1);
        if (pos < CAND_CAP)
            cand[pos] = ((u64)vb << 32) | (unsigned)(~n);
    }
}

// ---------------------------------------------------------------------------
// K4: bitonic-sort next_pow2(count) candidates (desc), take 64, gather output.
// Composite key => exact lax.top_k tie semantics (value desc, lower idx first).
// ---------------------------------------------------------------------------
__global__ __launch_bounds__(1024) void final_kernel(
    const u64* __restrict__ cand, const int* __restrict__ meta,
    const float* __restrict__ src, float* __restrict__ out)
{
    __shared__ u64 keys[CAND_CAP];
    __shared__ int idxs[64];
    const int t = threadIdx.x;

    int count = meta[0];
    if (count > CAND_CAP) count = CAND_CAP;
    int M = 64;
    while (M < count) M <<= 1;

    for (int i = t; i < M; i += 1024) keys[i] = (i < count) ? cand[i] : 0ULL;
    __syncthreads();

    for (int k = 2; k <= M; k <<= 1) {
        for (int j = k >> 1; j > 0; j >>= 1) {
            for (int i = t; i < M; i += 1024) {
                const int ixj = i ^ j;
                if (ixj > i) {
                    const u64 a = keys[i], b = keys[ixj];
                    const bool desc = (i & k) == 0;
                    if (desc ? (a < b) : (a > b)) { keys[i] = b; keys[ixj] = a; }
                }
            }
            __syncthreads();
        }
    }
    if (t < 64) idxs[t] = (int)~(unsigned)(keys[t] & 0xFFFFFFFFu);
    __syncthreads();

    // out[b, k, c] = src[b, c, idx[k]]  -> flat e = b*384 + k*6 + c
    for (int e = t; e < 3072; e += 1024) {
        const int b  = e / 384;
        const int r  = e % 384;
        const int kk = r / 6;
        const int c  = r % 6;
        out[e] = src[(b * 6 + c) * N_PTS + idxs[kk]];
    }
}

extern "C" void kernel_launch(void* const* d_in, const int* in_sizes, int n_in,
                              void* d_out, int out_size, void* d_ws, size_t ws_size,
                              hipStream_t stream)
{
    const float* src = (const float*)d_in[0];
    const float* W1 = (const float*)d_in[2];
    const float* b1 = (const float*)d_in[3];
    const float* W2 = (const float*)d_in[4];
    const float* b2 = (const float*)d_in[5];
    const float* Wa = (const float*)d_in[6];
    const float* ba = (const float*)d_in[7];
    const float* Wb = (const float*)d_in[8];
    const float* bb = (const float*)d_in[9];
    const float* Wc = (const float*)d_in[10];
    const float* bc = (const float*)d_in[11];

    char* ws = (char*)d_ws;
    float*    scores = (float*)ws;                          // 256 KB
    unsigned* hist   = (unsigned*)(ws + 256 * 1024);        // 128 KB
    u64*      cand   = (u64*)(ws + 384 * 1024);             // 16 KB
    int*      meta   = (int*)(ws + 400 * 1024);             // 16 B
    float*    out    = (float*)d_out;

    zero_kernel<<<128, 256, 0, stream>>>(hist, meta);
    score_kernel<<<256, 256, 0, stream>>>(src, W1, b1, W2, b2, Wa, ba,
                                          Wb, bb, Wc, bc, scores, hist);
    scan_kernel<<<1, 256, 0, stream>>>(hist, meta);
    compact_kernel<<<256, 256, 0, stream>>>(scores, meta, cand);
    final_kernel<<<1, 1024, 0, stream>>>(cand, meta, src, out);
}